// Round 9
// baseline (177.135 us; speedup 1.0000x reference)
//
#include <hip/hip_runtime.h>
#include <hip/hip_bf16.h>

typedef __bf16 bf16x8 __attribute__((ext_vector_type(8)));
typedef __bf16 bf16x4 __attribute__((ext_vector_type(4)));
typedef float f32x4 __attribute__((ext_vector_type(4)));

#define NROW 3072
#define NF 512            // IN_F == H*D == 512
#define NH 8
#define ND 64

// Order-preserving float<->uint key for atomicMax over signed floats.
__device__ __forceinline__ unsigned enc_key(float f) {
    unsigned u = __float_as_uint(f);
    return (f < 0.f) ? ~u : (u | 0x80000000u);
}
__device__ __forceinline__ float dec_key(unsigned k) {
    unsigned u = (k & 0x80000000u) ? (k ^ 0x80000000u) : ~k;
    return __uint_as_float(u);
}

// ---------------------------------------------------------------------------
// Kernel 0: W fp32 -> bf16 (once); init maxkey.
// ---------------------------------------------------------------------------
__global__ __launch_bounds__(256) void k_convW(const float* __restrict__ W,
                                               __bf16* __restrict__ Wb,
                                               unsigned* __restrict__ maxkey) {
    if (blockIdx.x == 0 && threadIdx.x < NH) maxkey[threadIdx.x] = 0u;
    int k = blockIdx.x * 256 + threadIdx.x;          // 65536 float4s
    float4 v = reinterpret_cast<const float4*>(W)[k];
    bf16x4 o = { (__bf16)v.x, (__bf16)v.y, (__bf16)v.z, (__bf16)v.w };
    *reinterpret_cast<bf16x4*>(Wb + k * 4) = o;
}

// ---------------------------------------------------------------------------
// Kernel 1: pack (adj>0 || j==i) into bitmask bits[3072][96] u32 (1.18 MB).
// ---------------------------------------------------------------------------
__global__ __launch_bounds__(256) void k_bitpack(const int* __restrict__ adj,
                                                 unsigned long long* __restrict__ bits64) {
    int i = blockIdx.x;
    int wave = threadIdx.x >> 6, lane = threadIdx.x & 63;
    const int* row = adj + i * NROW;
#pragma unroll
    for (int it = 0; it < 12; ++it) {
        int base = wave * 768 + it * 64;
        int j = base + lane;
        bool pred = (row[j] > 0) || (j == i);
        unsigned long long bal = __ballot(pred);
        if (lane == 0) bits64[i * 48 + (base >> 6)] = bal;
    }
}

// ---------------------------------------------------------------------------
// Kernel 2: h = x @ W^T; x converted fp32->bf16 in-register; write hT only
// (per-head d-major) via LDS transpose. 1536 blocks x 4 wave-tiles (16x16).
// ---------------------------------------------------------------------------
__global__ __launch_bounds__(256) void k_gemm(const float* __restrict__ x,
                                              const __bf16* __restrict__ Wb,
                                              __bf16* __restrict__ hT) {
    __shared__ __bf16 tile[4][16][17];
    int wave = threadIdx.x >> 6;
    int lane = threadIdx.x & 63;
    int t = blockIdx.x * 4 + wave;          // 6144 tiles: 192 i-tiles x 32 o-tiles
    int i0 = (t >> 5) << 4;
    int o0 = (t & 31) << 4;
    int fr = lane & 15;
    int quad = lane >> 4;

    const float* xp = x + (i0 + fr) * NF + quad * 8;
    const bf16x8* wp = reinterpret_cast<const bf16x8*>(Wb + (o0 + fr) * NF + quad * 8);

    f32x4 acc = {0.f, 0.f, 0.f, 0.f};
#pragma unroll
    for (int k = 0; k < 16; ++k) {
        float4 x0 = *reinterpret_cast<const float4*>(xp + k * 32);
        float4 x1 = *reinterpret_cast<const float4*>(xp + k * 32 + 4);
        bf16x8 a = { (__bf16)x0.x, (__bf16)x0.y, (__bf16)x0.z, (__bf16)x0.w,
                     (__bf16)x1.x, (__bf16)x1.y, (__bf16)x1.z, (__bf16)x1.w };
        bf16x8 b = wp[k * 4];
        acc = __builtin_amdgcn_mfma_f32_16x16x32_bf16(a, b, acc, 0, 0, 0);
    }
#pragma unroll
    for (int r = 0; r < 4; ++r)
        tile[wave][quad * 4 + r][fr] = (__bf16)acc[r];
    __syncthreads();
    int orow = lane >> 2;
    int li = (lane & 3) * 4;
    bf16x4 o4 = { tile[wave][li][orow], tile[wave][li + 1][orow],
                  tile[wave][li + 2][orow], tile[wave][li + 3][orow] };
    *reinterpret_cast<bf16x4*>(hT + (o0 + orow) * NROW + i0 + li) = o4;
}

// ---------------------------------------------------------------------------
// Kernel 3: e_srcT[h][i], e_dstT[h][i] from hT (coalesced row reads) + fused
// per-head global max. Grid dim3(12, 8).
// ---------------------------------------------------------------------------
__global__ __launch_bounds__(256) void k_edgesT(const __bf16* __restrict__ hT,
                                                const float* __restrict__ a_src,
                                                const float* __restrict__ a_dst,
                                                float* __restrict__ e_srcT,
                                                float* __restrict__ e_dstT,
                                                unsigned* __restrict__ maxkey) {
    int hh = blockIdx.y;
    int i = blockIdx.x * 256 + threadIdx.x;
    float ps = 0.f, pd = 0.f;
#pragma unroll
    for (int d = 0; d < ND; ++d) {
        float hv = (float)hT[(hh * ND + d) * NROW + i];
        ps += hv * a_src[hh * ND + d];
        pd += hv * a_dst[hh * ND + d];
    }
    e_srcT[hh * NROW + i] = ps;
    e_dstT[hh * NROW + i] = pd;
    float mx = pd;
#pragma unroll
    for (int off = 1; off < 64; off <<= 1) mx = fmaxf(mx, __shfl_xor(mx, off, 64));
    if ((threadIdx.x & 63) == 0) atomicMax(&maxkey[hh], enc_key(mx));
}

// ---------------------------------------------------------------------------
// Kernel 4: single-pass masked softmax-PV. Block = 32 i-rows (2 waves x 16)
// x one head; sweeps ALL 3072 j from a double-buffered LDS stage (48 chunks
// of 64 j, frag-ordered, conflict-free). den via MFMA-ones (acc4); divide
// in-register; write out directly (no num/den round-trip, no reduce kernel).
// Factored exp: p = mask * (P_j>T_i ? A_i*P_j : C_i*Q_j).
// Grid: 96 i-blocks x 8 heads = 768 blocks, 128 threads. LDS 40 KB -> 4/CU.
// ---------------------------------------------------------------------------
__global__ __launch_bounds__(128) void k_attn(const unsigned* __restrict__ bits,
                                              const float* __restrict__ e_srcT,
                                              const float* __restrict__ e_dstT,
                                              const unsigned* __restrict__ maxkey,
                                              const __bf16* __restrict__ hT,
                                              float* __restrict__ out) {
    constexpr int NC = NROW / 64;            // 48 chunks of 64 j
    __shared__ __align__(16) float2 lds_pq[NROW];        // 24 KB
    __shared__ __align__(16) __bf16 hbuf[2][4096];       // 2 x 8 KB
    int b = blockIdx.x;
    int head = b & 7;
    int i0 = (b >> 3) * 32;
    int tid = threadIdx.x;
    int wave = tid >> 6, lane = tid & 63;
    int fr = lane & 15, quad = lane >> 4;

    float Mg = dec_key(maxkey[head]);
    // pq fill: 6 rounds of float4 (coalesced)
#pragma unroll
    for (int r2 = 0; r2 < 6; ++r2) {
        int j4 = (r2 * 128 + tid) * 4;
        float4 e4 = *reinterpret_cast<const float4*>(e_dstT + head * NROW + j4);
        lds_pq[j4 + 0] = make_float2(__expf(e4.x - Mg), __expf(0.2f * (e4.x - Mg)));
        lds_pq[j4 + 1] = make_float2(__expf(e4.y - Mg), __expf(0.2f * (e4.y - Mg)));
        lds_pq[j4 + 2] = make_float2(__expf(e4.z - Mg), __expf(0.2f * (e4.z - Mg)));
        lds_pq[j4 + 3] = make_float2(__expf(e4.w - Mg), __expf(0.2f * (e4.w - Mg)));
    }

    // staging: 512 slots of 8 bf16; thread stages slots tid + r*128.
    // slot s -> jh=s>>8, dt=(s>>6)&3, fr=s&15, quad=(s>>4)&3;
    // src = hT[(head*64 + dt*16 + fr)*NROW + jh*32 + quad*8 + k*64]; dst = s*8.
    const __bf16* gp[4];
#pragma unroll
    for (int r = 0; r < 4; ++r) {
        int s = tid + r * 128;
        int jh = s >> 8, dt = (s >> 6) & 3, sfr = s & 15, sq = (s >> 4) & 3;
        gp[r] = hT + (head * ND + dt * 16 + sfr) * NROW + jh * 32 + sq * 8;
    }
#pragma unroll
    for (int r = 0; r < 4; ++r)
        *reinterpret_cast<bf16x8*>(&hbuf[0][tid * 8 + r * 1024]) =
            *reinterpret_cast<const bf16x8*>(gp[r]);

    int irow = i0 + wave * 16 + fr;
    float u = e_srcT[head * NROW + irow] + Mg;
    float A = (u > 0.f) ? 1.f : __expf(0.8f * u);
    float C = (u > 0.f) ? __expf(-0.8f * u) : 1.f;
    float T = __expf(-u);
    const unsigned* brow = bits + irow * 96;
    __syncthreads();

    const bf16x8 ones = { (__bf16)1.f, (__bf16)1.f, (__bf16)1.f, (__bf16)1.f,
                          (__bf16)1.f, (__bf16)1.f, (__bf16)1.f, (__bf16)1.f };
    f32x4 acc0 = {0,0,0,0}, acc1 = {0,0,0,0}, acc2 = {0,0,0,0}, acc3 = {0,0,0,0};
    f32x4 acc4 = {0,0,0,0};
    uint2 wm = *reinterpret_cast<const uint2*>(brow);

    for (int k = 0; k < NC; ++k) {
        bf16x8 st[4];
        uint2 wmn = wm;
        bool more = (k + 1 < NC);
        if (more) {
#pragma unroll
            for (int r = 0; r < 4; ++r)
                st[r] = *reinterpret_cast<const bf16x8*>(gp[r] + (k + 1) * 64);
            wmn = *reinterpret_cast<const uint2*>(brow + (k + 1) * 2);
        }
        const __bf16* hb = &hbuf[k & 1][0];
#pragma unroll
        for (int jh = 0; jh < 2; ++jh) {
            int j0 = k * 64 + jh * 32;
            unsigned w = (jh ? wm.y : wm.x) >> (quad * 8);
            bf16x8 v0 = *reinterpret_cast<const bf16x8*>(hb + jh * 2048 + 0 * 512 + lane * 8);
            bf16x8 v1 = *reinterpret_cast<const bf16x8*>(hb + jh * 2048 + 1 * 512 + lane * 8);
            bf16x8 v2 = *reinterpret_cast<const bf16x8*>(hb + jh * 2048 + 2 * 512 + lane * 8);
            bf16x8 v3 = *reinterpret_cast<const bf16x8*>(hb + jh * 2048 + 3 * 512 + lane * 8);
            const float4* lp = reinterpret_cast<const float4*>(&lds_pq[j0 + quad * 8]);
            float4 q01 = lp[0], q23 = lp[1], q45 = lp[2], q67 = lp[3];
            float P[8] = {q01.x, q01.z, q23.x, q23.z, q45.x, q45.z, q67.x, q67.z};
            float Q[8] = {q01.y, q01.w, q23.y, q23.w, q45.y, q45.w, q67.y, q67.w};
            bf16x8 af;
#pragma unroll
            for (int t = 0; t < 8; ++t) {
                bool pos = P[t] > T;
                float p = (pos ? P[t] : Q[t]) * (pos ? A : C);
                af[t] = ((w >> t) & 1u) ? (__bf16)p : (__bf16)0.f;
            }
            acc0 = __builtin_amdgcn_mfma_f32_16x16x32_bf16(af, v0, acc0, 0, 0, 0);
            acc1 = __builtin_amdgcn_mfma_f32_16x16x32_bf16(af, v1, acc1, 0, 0, 0);
            acc2 = __builtin_amdgcn_mfma_f32_16x16x32_bf16(af, v2, acc2, 0, 0, 0);
            acc3 = __builtin_amdgcn_mfma_f32_16x16x32_bf16(af, v3, acc3, 0, 0, 0);
            acc4 = __builtin_amdgcn_mfma_f32_16x16x32_bf16(af, ones, acc4, 0, 0, 0);
        }
        if (more) {
#pragma unroll
            for (int r = 0; r < 4; ++r)
                *reinterpret_cast<bf16x8*>(&hbuf[(k + 1) & 1][tid * 8 + r * 1024]) = st[r];
        }
        wm = wmn;
        __syncthreads();
    }

    // epilogue: acc4 rows hold den (replicated across cols); divide & store.
#pragma unroll
    for (int r = 0; r < 4; ++r) {
        float inv = 1.0f / fmaxf(acc4[r], 1e-30f);
        int orow = quad * 4 + r;
        int ob = (i0 + wave * 16 + orow) * NF + head * ND + fr;
        out[ob +  0] = acc0[r] * inv;
        out[ob + 16] = acc1[r] * inv;
        out[ob + 32] = acc2[r] * inv;
        out[ob + 48] = acc3[r] * inv;
    }
}

// ---------------------------------------------------------------------------
extern "C" void kernel_launch(void* const* d_in, const int* in_sizes, int n_in,
                              void* d_out, int out_size, void* d_ws, size_t ws_size,
                              hipStream_t stream) {
    const float* x_raw  = (const float*)d_in[0];
    const int*   adj    = (const int*)d_in[1];
    const float* W_raw  = (const float*)d_in[2];
    const float* as_raw = (const float*)d_in[3];
    const float* ad_raw = (const float*)d_in[4];
    float* out = (float*)d_out;

    char* ws = (char*)d_ws;
    __bf16*   hT     = (__bf16*)(ws);                    // 3,145,728 B
    float*    e_srcT = (float*)(ws + 3145728);           //    98,304 B
    float*    e_dstT = (float*)(ws + 3244032);           //    98,304 B
    unsigned* maxkey = (unsigned*)(ws + 3342336);        //        64 B
    unsigned* bits   = (unsigned*)(ws + 3342400);        // 1,179,648 B
    __bf16*   Wb     = (__bf16*)(ws + 4522048);          //   524,288 B
    // total 5,046,336 B

    k_convW<<<256, 256, 0, stream>>>(W_raw, Wb, maxkey);
    k_bitpack<<<NROW, 256, 0, stream>>>(adj, (unsigned long long*)bits);
    k_gemm<<<1536, 256, 0, stream>>>(x_raw, Wb, hT);
    k_edgesT<<<dim3(12, 8), 256, 0, stream>>>(hT, as_raw, ad_raw, e_srcT, e_dstT, maxkey);
    k_attn<<<96 * 8, 128, 0, stream>>>(bits, e_srcT, e_dstT, maxkey, hT, out);
}